// Round 1
// baseline (1278.240 us; speedup 1.0000x reference)
//
#include <hip/hip_runtime.h>
#include <hip/hip_bf16.h>

typedef __bf16  bf16x8 __attribute__((ext_vector_type(8)));
typedef float   f32x4  __attribute__((ext_vector_type(4)));
typedef int     i32x4  __attribute__((ext_vector_type(4)));

#define M_DIM 2048
#define K_DIM 2048
#define V_DIM 50257
#define BM 128
#define BN 128
#define BK 64
#define NT (K_DIM / BK)

// C = A(f32->bf16) * W(int8-in-int32 -> bf16), then *scale[n] + bias[n].
// A_lds[m][k], B_lds[n][k] both K-contiguous, XOR-swizzled 16B slots.
__global__ __launch_bounds__(256, 2)
void lmhead_gemm(const float* __restrict__ hs, const int* __restrict__ wq,
                 const float* __restrict__ scale, const float* __restrict__ bias,
                 float* __restrict__ out)
{
    __shared__ __attribute__((aligned(16))) __bf16 smem[2 * 2 * BM * BK]; // 64 KB

    const int tid  = threadIdx.x;
    const int lane = tid & 63;
    const int wv   = tid >> 6;
    const int wm   = wv >> 1;      // 0..1  (wave row)
    const int wn   = wv & 1;       // 0..1  (wave col)
    const int m0   = blockIdx.x * BM;
    const int n0   = blockIdx.y * BN;
    const bool edge = (n0 + BN > V_DIM);

    // B staging: each thread owns a 4n x 8k cell
    const int ngB = tid >> 3;      // 0..31 -> n = ngB*4
    const int kgB = tid & 7;       // 0..7  -> k = kgB*8

    float a_reg[4][8];
    int   b_reg[8][4];             // [j = k-within-group][i = n-within-4]

    f32x4 acc[4][4];
#pragma unroll
    for (int i = 0; i < 4; ++i)
#pragma unroll
        for (int j = 0; j < 4; ++j)
            acc[i][j] = (f32x4)(0.0f);

    auto load_tile = [&](int kt) {
        // A: cell c = tid + 256g : row = c>>3 (0..127), kg = c&7 (8 f32 along K)
#pragma unroll
        for (int g = 0; g < 4; ++g) {
            int c = tid + 256 * g;
            int row = c >> 3, kg = c & 7;
            const float* p = hs + (size_t)(m0 + row) * K_DIM + (size_t)kt * BK + kg * 8;
            f32x4 v0 = *(const f32x4*)p;
            f32x4 v1 = *(const f32x4*)(p + 4);
#pragma unroll
            for (int j = 0; j < 4; ++j) { a_reg[g][j] = v0[j]; a_reg[g][4 + j] = v1[j]; }
        }
        const int kbase = kt * BK + kgB * 8;
        if (!edge) {
            const int* p = wq + (size_t)kbase * V_DIM + n0 + ngB * 4;
#pragma unroll
            for (int j = 0; j < 8; ++j) {
                i32x4 v = *(const i32x4*)(p + (size_t)j * V_DIM);
#pragma unroll
                for (int i = 0; i < 4; ++i) b_reg[j][i] = v[i];
            }
        } else {
#pragma unroll
            for (int j = 0; j < 8; ++j) {
#pragma unroll
                for (int i = 0; i < 4; ++i) {
                    int n = n0 + ngB * 4 + i;
                    b_reg[j][i] = (n < V_DIM) ? wq[(size_t)(kbase + j) * V_DIM + n] : 0;
                }
            }
        }
    };

    auto store_tile = [&](int buf) {
        __bf16* As = smem + buf * (2 * BM * BK);
        __bf16* Bs = As + BM * BK;
#pragma unroll
        for (int g = 0; g < 4; ++g) {
            int c = tid + 256 * g;
            int row = c >> 3, kg = c & 7;
            bf16x8 t;
#pragma unroll
            for (int j = 0; j < 8; ++j) t[j] = (__bf16)a_reg[g][j];
            *(bf16x8*)(As + row * BK + ((kg * 8) ^ ((row & 7) << 3))) = t;
        }
        // B: transpose 4n x 8k -> rows of B_lds[n][k]
#pragma unroll
        for (int i = 0; i < 4; ++i) {
            int row = ngB * 4 + i;
            bf16x8 t;
#pragma unroll
            for (int j = 0; j < 8; ++j) t[j] = (__bf16)(float)b_reg[j][i];
            *(bf16x8*)(Bs + row * BK + ((kgB * 8) ^ ((row & 7) << 3))) = t;
        }
    };

    auto compute = [&](int buf) {
        const __bf16* As = smem + buf * (2 * BM * BK);
        const __bf16* Bs = As + BM * BK;
        const int hi = lane >> 4;
        const int la = lane & 15;
#pragma unroll
        for (int kk = 0; kk < 2; ++kk) {
            bf16x8 af[4], bfr[4];
#pragma unroll
            for (int f = 0; f < 4; ++f) {
                int row = wm * 64 + f * 16 + la;
                af[f] = *(const bf16x8*)(As + row * BK + ((kk * 32 + hi * 8) ^ ((row & 7) << 3)));
            }
#pragma unroll
            for (int f = 0; f < 4; ++f) {
                int row = wn * 64 + f * 16 + la;
                bfr[f] = *(const bf16x8*)(Bs + row * BK + ((kk * 32 + hi * 8) ^ ((row & 7) << 3)));
            }
#pragma unroll
            for (int fm = 0; fm < 4; ++fm)
#pragma unroll
                for (int fn = 0; fn < 4; ++fn)
                    acc[fm][fn] = __builtin_amdgcn_mfma_f32_16x16x32_bf16(
                        af[fm], bfr[fn], acc[fm][fn], 0, 0, 0);
        }
    };

    // --- pipeline: stage(0); loop { load(t+1); compute(t); write(t+1); sync; } compute(last)
    load_tile(0);
    store_tile(0);
    __syncthreads();
    int cur = 0;
#pragma unroll 1
    for (int kt = 0; kt < NT - 1; ++kt) {
        load_tile(kt + 1);     // global loads in flight under compute
        compute(cur);
        store_tile(cur ^ 1);   // vmcnt wait + convert + ds_write
        __syncthreads();
        cur ^= 1;
    }
    compute(cur);

    // --- epilogue: D row=(lane>>4)*4+r, col=lane&15
    const int hi = lane >> 4;
    const int la = lane & 15;
#pragma unroll
    for (int fn = 0; fn < 4; ++fn) {
        int n = n0 + wn * 64 + fn * 16 + la;
        bool ok = (n < V_DIM);
        int nc = ok ? n : 0;
        float sc = scale[nc];
        float bi = bias[nc];
#pragma unroll
        for (int fm = 0; fm < 4; ++fm) {
            int m = m0 + wm * 64 + fm * 16 + hi * 4;
            float* op = out + (size_t)m * V_DIM + n;
#pragma unroll
            for (int r = 0; r < 4; ++r) {
                if (ok) op[(size_t)r * V_DIM] = acc[fm][fn][r] * sc + bi;
            }
        }
    }
}

extern "C" void kernel_launch(void* const* d_in, const int* in_sizes, int n_in,
                              void* d_out, int out_size, void* d_ws, size_t ws_size,
                              hipStream_t stream) {
    const float* hs    = (const float*)d_in[0];
    const int*   wq    = (const int*)d_in[1];
    const float* scale = (const float*)d_in[2];
    const float* bias  = (const float*)d_in[3];
    float*       out   = (float*)d_out;

    dim3 grid(M_DIM / BM, (V_DIM + BN - 1) / BN);  // (16, 393); x fast-varying -> M-blocks
                                                   // of one weight panel run concurrently
    lmhead_gemm<<<grid, dim3(256, 1, 1), 0, stream>>>(hs, wq, scale, bias, out);
}

// Round 2
// 714.526 us; speedup vs baseline: 1.7889x; 1.7889x over previous
//
#include <hip/hip_runtime.h>
#include <hip/hip_bf16.h>

typedef __bf16  bf16x8 __attribute__((ext_vector_type(8)));
typedef __bf16  bf16x4 __attribute__((ext_vector_type(4)));
typedef float   f32x4  __attribute__((ext_vector_type(4)));
typedef int     i32x4  __attribute__((ext_vector_type(4)));

#define M_DIM 2048
#define K_DIM 2048
#define V_DIM 50257
#define V_PAD 50304                 // 393 * 128
#define BM 128
#define BN 128
#define BK 64
#define NT (K_DIM / BK)

__device__ __forceinline__ void gl_lds16(const __bf16* g, __bf16* l) {
    __builtin_amdgcn_global_load_lds(
        (const __attribute__((address_space(1))) void*)g,
        (__attribute__((address_space(3))) void*)l, 16, 0, 0);
}

// ---------- prepass 1: A f32 -> bf16 (2048x2048) ----------
__global__ __launch_bounds__(256)
void cvtA(const float* __restrict__ hs, __bf16* __restrict__ a) {
    int i = (blockIdx.x * 256 + threadIdx.x) * 8;          // grid exactly covers 4M elems
    f32x4 v0 = *(const f32x4*)(hs + i);
    f32x4 v1 = *(const f32x4*)(hs + i + 4);
    bf16x8 t;
#pragma unroll
    for (int j = 0; j < 4; ++j) { t[j] = (__bf16)v0[j]; t[4 + j] = (__bf16)v1[j]; }
    *(bf16x8*)(a + i) = t;
}

// ---------- prepass 2: W[k][v] int32 -> Wt[v][k] bf16, zero-padded to V_PAD ----------
__global__ __launch_bounds__(256)
void cvtW(const int* __restrict__ wq, __bf16* __restrict__ wt) {
    __shared__ __attribute__((aligned(16))) __bf16 tls[64][72];
    const int t  = threadIdx.x;
    const int v0 = blockIdx.x * 64;
    const int k0 = blockIdx.y * 64;
    const int vb = t & 15, kb = t >> 4;
    const bool edge = (v0 + 64 > V_DIM);

    __bf16 cv[4][4];                                      // [j=k][i=v]
#pragma unroll
    for (int j = 0; j < 4; ++j) {
        const int* p = wq + (size_t)(k0 + kb * 4 + j) * V_DIM + v0 + vb * 4;
        if (!edge) {
            i32x4 w = *(const i32x4*)p;
#pragma unroll
            for (int i = 0; i < 4; ++i) cv[j][i] = (__bf16)(float)w[i];
        } else {
#pragma unroll
            for (int i = 0; i < 4; ++i) {
                int v = v0 + vb * 4 + i;
                cv[j][i] = (v < V_DIM) ? (__bf16)(float)p[i] : (__bf16)0.0f;
            }
        }
    }
#pragma unroll
    for (int i = 0; i < 4; ++i) {
        bf16x4 c = { cv[0][i], cv[1][i], cv[2][i], cv[3][i] };
        *(bf16x4*)(&tls[vb * 4 + i][kb * 4]) = c;
    }
    __syncthreads();
    const int v = t >> 2, ko = (t & 3) * 16;
    bf16x8 r0 = *(const bf16x8*)(&tls[v][ko]);
    bf16x8 r1 = *(const bf16x8*)(&tls[v][ko + 8]);
    __bf16* op = wt + (size_t)(v0 + v) * K_DIM + k0 + ko;
    *(bf16x8*)op = r0;
    *(bf16x8*)(op + 8) = r1;
}

// ---------- main GEMM: C = Abf[2048x2048] * Wt^T, *scale + bias ----------
// m97 structure: 128x128 tile, BK=64, single LDS buffer, 2 barriers/K-step,
// global_load_lds width-16 staging, linear LDS [row][64].
__global__ __launch_bounds__(256, 2)
void lmhead_gemm_bf16(const __bf16* __restrict__ A, const __bf16* __restrict__ Bt,
                      const float* __restrict__ scale, const float* __restrict__ bias,
                      float* __restrict__ out)
{
    __shared__ __attribute__((aligned(16))) __bf16 As[BM * BK];   // 16 KB
    __shared__ __attribute__((aligned(16))) __bf16 Bs[BN * BK];   // 16 KB

    const int tid  = threadIdx.x;
    const int lane = tid & 63;
    const int wv   = tid >> 6;
    const int wm   = wv >> 1, wn = wv & 1;

    // bijective XCD-chunked swizzle: 6288 blocks, 6288/8 = 786 exact.
    int bid  = blockIdx.x;
    int wgid = (bid & 7) * 786 + (bid >> 3);
    const int m0 = (wgid & 15) * BM;          // M fast-varying within an XCD chunk
    const int n0 = (wgid >> 4) * BN;

    const int hi = lane >> 4, la = lane & 15;

    f32x4 acc[4][4];
#pragma unroll
    for (int i = 0; i < 4; ++i)
#pragma unroll
        for (int j = 0; j < 4; ++j) acc[i][j] = (f32x4)(0.0f);

#pragma unroll 1
    for (int kt = 0; kt < NT; ++kt) {
        // ---- stage: 16 KB each of A,B via 8 gload_lds(1KB) per wave ----
        const int l8 = lane >> 3, l7 = lane & 7;
#pragma unroll
        for (int i = 0; i < 4; ++i) {
            int seg = wv * 4 + i;                                // 0..15, wave-uniform
            int row = seg * 8 + l8;
            gl_lds16(A  + (size_t)(m0 + row) * K_DIM + kt * BK + l7 * 8, As + seg * 512);
            gl_lds16(Bt + (size_t)(n0 + row) * K_DIM + kt * BK + l7 * 8, Bs + seg * 512);
        }
        __syncthreads();   // drains vmcnt(0): tiles resident

        // ---- compute: 16 ds_read_b128 + 32 MFMA per wave ----
#pragma unroll
        for (int kk = 0; kk < 2; ++kk) {
            bf16x8 af[4], bf[4];
#pragma unroll
            for (int f = 0; f < 4; ++f)
                af[f] = *(const bf16x8*)(As + (wm * 64 + f * 16 + la) * BK + kk * 32 + hi * 8);
#pragma unroll
            for (int f = 0; f < 4; ++f)
                bf[f] = *(const bf16x8*)(Bs + (wn * 64 + f * 16 + la) * BK + kk * 32 + hi * 8);
#pragma unroll
            for (int fm = 0; fm < 4; ++fm)
#pragma unroll
                for (int fn = 0; fn < 4; ++fn)
                    acc[fm][fn] = __builtin_amdgcn_mfma_f32_16x16x32_bf16(
                        af[fm], bf[fn], acc[fm][fn], 0, 0, 0);
        }
        __syncthreads();   // compute done before next overwrite
    }

    // ---- epilogue: D row = hi*4+r (A/m side), col = la (B/n side) ----
#pragma unroll
    for (int fn = 0; fn < 4; ++fn) {
        int n = n0 + wn * 64 + fn * 16 + la;
        bool ok = (n < V_DIM);
        int nc = ok ? n : 0;
        float sc = scale[nc];
        float bi = bias[nc];
#pragma unroll
        for (int fm = 0; fm < 4; ++fm) {
            int m = m0 + wm * 64 + fm * 16 + hi * 4;
            float* op = out + (size_t)m * V_DIM + n;
#pragma unroll
            for (int r = 0; r < 4; ++r)
                if (ok) op[(size_t)r * V_DIM] = acc[fm][fn][r] * sc + bi;
        }
    }
}

// ================= fallback (R0 kernel, used only if ws too small) =================
__global__ __launch_bounds__(256, 2)
void lmhead_gemm_fb(const float* __restrict__ hs, const int* __restrict__ wq,
                    const float* __restrict__ scale, const float* __restrict__ bias,
                    float* __restrict__ out)
{
    __shared__ __attribute__((aligned(16))) __bf16 smem[2 * 2 * BM * BK];
    const int tid  = threadIdx.x;
    const int lane = tid & 63;
    const int wv   = tid >> 6;
    const int wm   = wv >> 1, wn = wv & 1;
    const int m0   = blockIdx.x * BM;
    const int n0   = blockIdx.y * BN;
    const bool edge = (n0 + BN > V_DIM);
    const int ngB = tid >> 3, kgB = tid & 7;

    float a_reg[4][8];
    int   b_reg[8][4];
    f32x4 acc[4][4];
#pragma unroll
    for (int i = 0; i < 4; ++i)
#pragma unroll
        for (int j = 0; j < 4; ++j) acc[i][j] = (f32x4)(0.0f);

    auto load_tile = [&](int kt) {
#pragma unroll
        for (int g = 0; g < 4; ++g) {
            int c = tid + 256 * g;
            int row = c >> 3, kg = c & 7;
            const float* p = hs + (size_t)(m0 + row) * K_DIM + (size_t)kt * BK + kg * 8;
            f32x4 v0 = *(const f32x4*)p;
            f32x4 v1 = *(const f32x4*)(p + 4);
#pragma unroll
            for (int j = 0; j < 4; ++j) { a_reg[g][j] = v0[j]; a_reg[g][4 + j] = v1[j]; }
        }
        const int kbase = kt * BK + kgB * 8;
        if (!edge) {
            const int* p = wq + (size_t)kbase * V_DIM + n0 + ngB * 4;
#pragma unroll
            for (int j = 0; j < 8; ++j) {
                i32x4 v = *(const i32x4*)(p + (size_t)j * V_DIM);
#pragma unroll
                for (int i = 0; i < 4; ++i) b_reg[j][i] = v[i];
            }
        } else {
#pragma unroll
            for (int j = 0; j < 8; ++j)
#pragma unroll
                for (int i = 0; i < 4; ++i) {
                    int n = n0 + ngB * 4 + i;
                    b_reg[j][i] = (n < V_DIM) ? wq[(size_t)(kbase + j) * V_DIM + n] : 0;
                }
        }
    };
    auto store_tile = [&](int buf) {
        __bf16* As = smem + buf * (2 * BM * BK);
        __bf16* Bs = As + BM * BK;
#pragma unroll
        for (int g = 0; g < 4; ++g) {
            int c = tid + 256 * g;
            int row = c >> 3, kg = c & 7;
            bf16x8 t;
#pragma unroll
            for (int j = 0; j < 8; ++j) t[j] = (__bf16)a_reg[g][j];
            *(bf16x8*)(As + row * BK + ((kg * 8) ^ ((row & 7) << 3))) = t;
        }
#pragma unroll
        for (int i = 0; i < 4; ++i) {
            int row = ngB * 4 + i;
            bf16x8 t;
#pragma unroll
            for (int j = 0; j < 8; ++j) t[j] = (__bf16)(float)b_reg[j][i];
            *(bf16x8*)(Bs + row * BK + ((kgB * 8) ^ ((row & 7) << 3))) = t;
        }
    };
    auto compute = [&](int buf) {
        const __bf16* As = smem + buf * (2 * BM * BK);
        const __bf16* Bs = As + BM * BK;
        const int hi = lane >> 4, la = lane & 15;
#pragma unroll
        for (int kk = 0; kk < 2; ++kk) {
            bf16x8 af[4], bfr[4];
#pragma unroll
            for (int f = 0; f < 4; ++f) {
                int row = wm * 64 + f * 16 + la;
                af[f] = *(const bf16x8*)(As + row * BK + ((kk * 32 + hi * 8) ^ ((row & 7) << 3)));
            }
#pragma unroll
            for (int f = 0; f < 4; ++f) {
                int row = wn * 64 + f * 16 + la;
                bfr[f] = *(const bf16x8*)(Bs + row * BK + ((kk * 32 + hi * 8) ^ ((row & 7) << 3)));
            }
#pragma unroll
            for (int fm = 0; fm < 4; ++fm)
#pragma unroll
                for (int fn = 0; fn < 4; ++fn)
                    acc[fm][fn] = __builtin_amdgcn_mfma_f32_16x16x32_bf16(
                        af[fm], bfr[fn], acc[fm][fn], 0, 0, 0);
        }
    };

    load_tile(0); store_tile(0); __syncthreads();
    int cur = 0;
#pragma unroll 1
    for (int kt = 0; kt < NT - 1; ++kt) {
        load_tile(kt + 1);
        compute(cur);
        store_tile(cur ^ 1);
        __syncthreads();
        cur ^= 1;
    }
    compute(cur);

    const int hi = lane >> 4, la = lane & 15;
#pragma unroll
    for (int fn = 0; fn < 4; ++fn) {
        int n = n0 + wn * 64 + fn * 16 + la;
        bool ok = (n < V_DIM);
        int nc = ok ? n : 0;
        float sc = scale[nc];
        float bi = bias[nc];
#pragma unroll
        for (int fm = 0; fm < 4; ++fm) {
            int m = m0 + wm * 64 + fm * 16 + hi * 4;
            float* op = out + (size_t)m * V_DIM + n;
#pragma unroll
            for (int r = 0; r < 4; ++r)
                if (ok) op[(size_t)r * V_DIM] = acc[fm][fn][r] * sc + bi;
        }
    }
}

extern "C" void kernel_launch(void* const* d_in, const int* in_sizes, int n_in,
                              void* d_out, int out_size, void* d_ws, size_t ws_size,
                              hipStream_t stream) {
    const float* hs    = (const float*)d_in[0];
    const int*   wq    = (const int*)d_in[1];
    const float* scale = (const float*)d_in[2];
    const float* bias  = (const float*)d_in[3];
    float*       out   = (float*)d_out;

    const size_t needA = (size_t)M_DIM * K_DIM * 2;               // 8 MB
    const size_t needW = (size_t)V_PAD * K_DIM * 2;               // 206 MB
    if (ws_size >= needA + needW) {
        __bf16* Abf = (__bf16*)d_ws;
        __bf16* Wt  = (__bf16*)((char*)d_ws + needA);
        cvtA<<<dim3(M_DIM * K_DIM / (256 * 8)), dim3(256), 0, stream>>>(hs, Abf);
        cvtW<<<dim3(V_PAD / 64, K_DIM / 64), dim3(256), 0, stream>>>(wq, Wt);
        lmhead_gemm_bf16<<<dim3(16 * (V_PAD / BN)), dim3(256), 0, stream>>>(
            Abf, Wt, scale, bias, out);
    } else {
        lmhead_gemm_fb<<<dim3(M_DIM / BM, (V_DIM + BN - 1) / BN), dim3(256), 0, stream>>>(
            hs, wq, scale, bias, out);
    }
}